// Round 2
// baseline (79409.473 us; speedup 1.0000x reference)
//
#include <hip/hip_runtime.h>
#include <cstddef>

static constexpr float LCA_LAMBDA = 0.5f;
static constexpr float LCA_ETA    = 1.0f / 1000.0f;

// ---------------------------------------------------------------- utilities

__global__ void zero_kernel(float* __restrict__ p, int n) {
  int i = blockIdx.x * blockDim.x + threadIdx.x;
  if (i < n) p[i] = 0.f;
}

// per-sample standardize over C*H*W (population std, eps 1e-8 on std)
__global__ __launch_bounds__(256) void standardize_kernel(
    const float* __restrict__ in, float* __restrict__ out, int CHW) {
  int n = blockIdx.x;
  const float* src = in + (size_t)n * CHW;
  float* dst = out + (size_t)n * CHW;
  int t = threadIdx.x;
  float s = 0.f, ss = 0.f;
  for (int i = t; i < CHW; i += 256) { float v = src[i]; s += v; ss += v * v; }
  __shared__ float red0[256], red1[256];
  red0[t] = s; red1[t] = ss;
  __syncthreads();
  for (int off = 128; off > 0; off >>= 1) {
    if (t < off) { red0[t] += red0[t + off]; red1[t] += red1[t + off]; }
    __syncthreads();
  }
  float m = red0[0] / (float)CHW;
  float var = red1[0] / (float)CHW - m * m;
  var = fmaxf(var, 0.f);
  float inv = 1.0f / (sqrtf(var) + 1e-8f);
  for (int i = t; i < CHW; i += 256) dst[i] = (src[i] - m) * inv;
}

// BatchNorm2d training-mode math over (N,H,W) per channel; optional input
// transform a=relu(u-lambda) (used to read LCA's final u directly).
template <bool TRANSFORM>
__global__ __launch_bounds__(256) void bn_kernel(
    const float* __restrict__ in, float* __restrict__ out,
    const float* __restrict__ gamma, const float* __restrict__ beta,
    int C, int HW, int N) {
  int c = blockIdx.x;
  int t = threadIdx.x;
  float s = 0.f, ss = 0.f;
  for (int n = 0; n < N; ++n) {
    const float* src = in + ((size_t)n * C + c) * HW;
    for (int i = t; i < HW; i += 256) {
      float v = src[i];
      if (TRANSFORM) v = fmaxf(v - LCA_LAMBDA, 0.f);
      s += v; ss += v * v;
    }
  }
  __shared__ float red0[256], red1[256];
  red0[t] = s; red1[t] = ss;
  __syncthreads();
  for (int off = 128; off > 0; off >>= 1) {
    if (t < off) { red0[t] += red0[t + off]; red1[t] += red1[t + off]; }
    __syncthreads();
  }
  float cnt = (float)(N * HW);
  float m = red0[0] / cnt;
  float var = red1[0] / cnt - m * m;
  var = fmaxf(var, 0.f);
  float scale = gamma[c] * rsqrtf(var + 1e-5f);
  float shift = beta[c] - m * scale;
  for (int n = 0; n < N; ++n) {
    const float* src = in + ((size_t)n * C + c) * HW;
    float* dst = out + ((size_t)n * C + c) * HW;
    for (int i = t; i < HW; i += 256) {
      float v = src[i];
      if (TRANSFORM) v = fmaxf(v - LCA_LAMBDA, 0.f);
      dst[i] = v * scale + shift;
    }
  }
}

// Feature Gram kernel G[i][j][p][q] = sum_{c,ky,kx} w[i,c,p+ky-4,q+kx-4]*w[j,c,ky,kx]
// stored padded: Gp[i][j][p][12] (q 0..8 valid, 9..11 zero) for float4 loads.
__global__ void gram_kernel(const float* __restrict__ w, float* __restrict__ Gp,
                            int F, int Cin) {
  int idx = blockIdx.x * blockDim.x + threadIdx.x;
  int tot = F * F * 9 * 12;
  if (idx >= tot) return;
  int q = idx % 12;
  int p = (idx / 12) % 9;
  int j = (idx / 108) % F;
  int i = idx / (108 * F);
  float acc = 0.f;
  if (q < 9) {
    int ky0 = max(0, 4 - p), ky1 = min(4, 8 - p);
    int kx0 = max(0, 4 - q), kx1 = min(4, 8 - q);
    for (int c = 0; c < Cin; ++c) {
      const float* wi = w + ((size_t)i * Cin + c) * 25;
      const float* wj = w + ((size_t)j * Cin + c) * 25;
      for (int ky = ky0; ky <= ky1; ++ky)
        for (int kx = kx0; kx <= kx1; ++kx)
          acc += wi[(p + ky - 4) * 5 + (q + kx - 4)] * wj[ky * 5 + kx];
    }
  }
  Gp[idx] = acc;
}

// generic 5x5 pad-2 cross-correlation (NCHW / OIHW), optional bias+relu
__global__ void conv5x5_kernel(const float* __restrict__ in,
                               const float* __restrict__ w,
                               const float* __restrict__ bias,
                               float* __restrict__ out,
                               int N, int Ci, int Co, int H, int W, int do_relu) {
  int idx = blockIdx.x * blockDim.x + threadIdx.x;
  int tot = N * Co * H * W;
  if (idx >= tot) return;
  int x = idx % W;
  int y = (idx / W) % H;
  int co = (idx / (W * H)) % Co;
  int n = idx / (W * H * Co);
  float acc = bias ? bias[co] : 0.f;
  for (int c = 0; c < Ci; ++c) {
    const float* ip = in + ((size_t)n * Ci + c) * H * W;
    const float* wp = w + ((size_t)co * Ci + c) * 25;
#pragma unroll
    for (int ky = 0; ky < 5; ++ky) {
      int yy = y + ky - 2;
      if (yy < 0 || yy >= H) continue;
#pragma unroll
      for (int kx = 0; kx < 5; ++kx) {
        int xx = x + kx - 2;
        if (xx < 0 || xx >= W) continue;
        acc = fmaf(ip[yy * W + xx], wp[ky * 5 + kx], acc);
      }
    }
  }
  if (do_relu) acc = fmaxf(acc, 0.f);
  out[idx] = acc;
}

template <bool TRANSFORM>
__global__ void maxpool_kernel(const float* __restrict__ in, float* __restrict__ out,
                               int N, int C, int Ho, int Wo) {
  int idx = blockIdx.x * blockDim.x + threadIdx.x;
  int tot = N * C * Ho * Wo;
  if (idx >= tot) return;
  int x = idx % Wo;
  int y = (idx / Wo) % Ho;
  int c = (idx / (Wo * Ho)) % C;
  int n = idx / (Wo * Ho * C);
  int H = Ho * 2, W = Wo * 2;
  const float* ip = in + (((size_t)n * C + c) * H + 2 * y) * W + 2 * x;
  float v0 = ip[0], v1 = ip[1], v2 = ip[W], v3 = ip[W + 1];
  if (TRANSFORM) {
    v0 = fmaxf(v0 - LCA_LAMBDA, 0.f);
    v1 = fmaxf(v1 - LCA_LAMBDA, 0.f);
    v2 = fmaxf(v2 - LCA_LAMBDA, 0.f);
    v3 = fmaxf(v3 - LCA_LAMBDA, 0.f);
  }
  out[idx] = fmaxf(fmaxf(v0, v1), fmaxf(v2, v3));
}

template <bool RELU>
__global__ __launch_bounds__(64) void fc_kernel(
    const float* __restrict__ in, const float* __restrict__ w,
    const float* __restrict__ bias, float* __restrict__ out, int K) {
  int o = blockIdx.x;   // output feature
  int n = blockIdx.y;   // sample
  int Osz = gridDim.x;
  const float* ip = in + (size_t)n * K;
  const float* wp = w + (size_t)o * K;
  float s = 0.f;
  for (int k = threadIdx.x; k < K; k += 64) s = fmaf(ip[k], wp[k], s);
  for (int off = 32; off > 0; off >>= 1) s += __shfl_down(s, off, 64);
  if (threadIdx.x == 0) {
    s += bias[o];
    if (RELU) s = fmaxf(s, 0.f);
    out[(size_t)n * Osz + o] = s;
  }
}

// ----------------------------------------------------------- grid barrier
// Two-level sense-free (generation) barrier. bar layout (ints):
//   [0..255]   16 leaf counters, one per 64B line (index l*16)
//   [256]      root counter
//   [272]      generation
// All zeroed before launch. Device-scope atomics reach the coherence point
// (LLC) across XCDs; __threadfence() release/acquire orders the u-field
// stores/loads (emits L2 writeback + L1/L2 invalidate on gfx950).
__device__ __forceinline__ void grid_barrier(int* bar, int bid, int nblocks) {
  __syncthreads();   // drains this block's vmem stores (waitcnt before barrier)
  if (threadIdx.x == 0) {
    __threadfence();  // release: flush our writes toward LLC
    int* leaf = bar + ((bid & 15) << 4);
    int* root = bar + 256;
    int* gen  = bar + 272;
    int g = __hip_atomic_load(gen, __ATOMIC_RELAXED, __HIP_MEMORY_SCOPE_AGENT);
    int per_leaf = nblocks >> 4;
    if (__hip_atomic_fetch_add(leaf, 1, __ATOMIC_ACQ_REL,
                               __HIP_MEMORY_SCOPE_AGENT) == per_leaf - 1) {
      __hip_atomic_store(leaf, 0, __ATOMIC_RELEASE, __HIP_MEMORY_SCOPE_AGENT);
      if (__hip_atomic_fetch_add(root, 1, __ATOMIC_ACQ_REL,
                                 __HIP_MEMORY_SCOPE_AGENT) == 15) {
        __hip_atomic_store(root, 0, __ATOMIC_RELEASE, __HIP_MEMORY_SCOPE_AGENT);
        __hip_atomic_fetch_add(gen, 1, __ATOMIC_RELEASE, __HIP_MEMORY_SCOPE_AGENT);
      }
    }
    while (__hip_atomic_load(gen, __ATOMIC_ACQUIRE, __HIP_MEMORY_SCOPE_AGENT) == g) {
      __builtin_amdgcn_s_sleep(1);
    }
    __threadfence();  // acquire: invalidate stale L1/L2 lines before reads
  }
  __syncthreads();
}

// ------------------------------------------------------ persistent LCA solve
// All 500 iterations in one kernel; u ping-pongs between uA/uB (global),
// one grid barrier per iteration. Block = 128 threads = 2 waves; each wave
// handles half the g (input-feature) sum, partials combined in LDS -> twice
// the SIMD coverage of the 64-thread layout. Wave layout: lane = 8 xg (4
// consecutive x each) x 8 features. Block owns (n, y, 8-feature group).
// Grid (1-D): C/8 * 32 * 4 blocks; all co-resident (LDS 23/46 KB -> >=3/CU).
template <int C>
__global__ __launch_bounds__(128) void lca_persistent_kernel(
    const float* __restrict__ drive, float* __restrict__ uA,
    float* __restrict__ uB, const float* __restrict__ Gp,
    int* __restrict__ bar, int iters) {
  constexpr int FG = C / 8;          // feature groups
  const int nblocks = FG * 32 * 4;
  __shared__ float slab[9 * C * 40]; // [p][g][40]
  __shared__ float partial[64 * 4];

  const int tid = threadIdx.x;
  const int bid = blockIdx.x;
  const int fg = bid % FG;
  const int y  = (bid / FG) % 32;
  const int n  = bid / (FG * 32);

  const int w    = tid >> 6;         // g-half
  const int lane = tid & 63;
  const int xg   = lane & 7, x0 = xg * 4;
  const int f    = fg * 8 + (lane >> 3);
  const int glo  = w * (C / 2), ghi = glo + (C / 2);

  const size_t o = (((size_t)n * C + f) * 32 + y) * 32 + x0;
  const int TOT = 9 * C * 40;

  for (int it = 0; it < iters; ++it) {
    const float* u_in = (it & 1) ? uB : uA;
    float* u_out      = (it & 1) ? uA : uB;

    // stage a = relu(u - lambda) slab for rows y-4..y+4, x padded to 40
    const float* ub = u_in + (size_t)n * C * 1024;
    for (int idx = tid; idx < TOT; idx += 128) {
      int xs_ = idx % 40;
      int rest = idx / 40;
      int g = rest % C;
      int p = rest / C;
      int yy = y + p - 4;
      int xx = xs_ - 4;
      float v = 0.f;
      if (yy >= 0 && yy < 32 && xx >= 0 && xx < 32)
        v = fmaxf(ub[(g * 32 + yy) * 32 + xx] - LCA_LAMBDA, 0.f);
      slab[idx] = v;
    }
    __syncthreads();

    float acc0 = 0.f, acc1 = 0.f, acc2 = 0.f, acc3 = 0.f;
    for (int g = glo; g < ghi; ++g) {
      const float* srow = &slab[g * 40 + x0];
      const float4* grow = (const float4*)Gp + ((size_t)f * C + g) * 27;
#pragma unroll
      for (int p = 0; p < 9; ++p) {
        const float* s = srow + p * (C * 40);
        float4 a0 = *(const float4*)(s);
        float4 a1 = *(const float4*)(s + 4);
        float4 a2 = *(const float4*)(s + 8);
        float4 g0 = grow[p * 3], g1 = grow[p * 3 + 1], g2 = grow[p * 3 + 2];
        float wv[12] = {a0.x, a0.y, a0.z, a0.w, a1.x, a1.y,
                        a1.z, a1.w, a2.x, a2.y, a2.z, a2.w};
        float gv[9] = {g0.x, g0.y, g0.z, g0.w, g1.x, g1.y, g1.z, g1.w, g2.x};
#pragma unroll
        for (int q = 0; q < 9; ++q) {
          acc0 = fmaf(wv[q + 0], gv[q], acc0);
          acc1 = fmaf(wv[q + 1], gv[q], acc1);
          acc2 = fmaf(wv[q + 2], gv[q], acc2);
          acc3 = fmaf(wv[q + 3], gv[q], acc3);
        }
      }
    }

    if (w == 1) {
      partial[lane * 4 + 0] = acc0;
      partial[lane * 4 + 1] = acc1;
      partial[lane * 4 + 2] = acc2;
      partial[lane * 4 + 3] = acc3;
    }
    __syncthreads();
    if (w == 0) {
      acc0 += partial[lane * 4 + 0];
      acc1 += partial[lane * 4 + 1];
      acc2 += partial[lane * 4 + 2];
      acc3 += partial[lane * 4 + 3];
      float4 uo = *(const float4*)(u_in + o);
      float4 dv = *(const float4*)(drive + o);
      float4 r;
      float a;
      a = fmaxf(uo.x - LCA_LAMBDA, 0.f);
      r.x = uo.x + LCA_ETA * (dv.x - uo.x - acc0 + a);
      a = fmaxf(uo.y - LCA_LAMBDA, 0.f);
      r.y = uo.y + LCA_ETA * (dv.y - uo.y - acc1 + a);
      a = fmaxf(uo.z - LCA_LAMBDA, 0.f);
      r.z = uo.z + LCA_ETA * (dv.z - uo.z - acc2 + a);
      a = fmaxf(uo.w - LCA_LAMBDA, 0.f);
      r.w = uo.w + LCA_ETA * (dv.w - uo.w - acc3 + a);
      *(float4*)(u_out + o) = r;
    }

    grid_barrier(bar, bid, nblocks);
  }
}

// ------------------------------------------------------------------ launcher

extern "C" void kernel_launch(void* const* d_in, const int* in_sizes, int n_in,
                              void* d_out, int out_size, void* d_ws, size_t ws_size,
                              hipStream_t stream) {
  const float* x       = (const float*)d_in[0];
  const float* w_lca1  = (const float*)d_in[1];
  const float* w_lca2  = (const float*)d_in[2];
  const float* bn1_g   = (const float*)d_in[3];
  const float* bn1_b   = (const float*)d_in[4];
  const float* bn2_g   = (const float*)d_in[5];
  const float* bn2_b   = (const float*)d_in[6];
  const float* w_conv1 = (const float*)d_in[7];
  const float* b_conv1 = (const float*)d_in[8];
  const float* bn3_g   = (const float*)d_in[9];
  const float* bn3_b   = (const float*)d_in[10];
  const float* w_conv2 = (const float*)d_in[11];
  const float* b_conv2 = (const float*)d_in[12];
  const float* bn4_g   = (const float*)d_in[13];
  const float* bn4_b   = (const float*)d_in[14];
  const float* w_conv3 = (const float*)d_in[15];
  const float* b_conv3 = (const float*)d_in[16];
  const float* bn5_g   = (const float*)d_in[17];
  const float* bn5_b   = (const float*)d_in[18];
  const float* w_fc1   = (const float*)d_in[19];
  const float* b_fc1   = (const float*)d_in[20];
  const float* w_fc2   = (const float*)d_in[21];
  const float* b_fc2   = (const float*)d_in[22];
  float* outp = (float*)d_out;

  float* ws = (float*)d_ws;
  size_t off = 0;
  auto alloc = [&](size_t nelem) {
    float* p = ws + off;
    off += (nelem + 63) & ~(size_t)63;
    return p;
  };
  float* xs     = alloc(4 * 3 * 32 * 32);
  float* Gp1    = alloc(16 * 16 * 9 * 12);
  float* Gp2    = alloc(32 * 32 * 9 * 12);
  float* drive1 = alloc(65536);
  float* uA1    = alloc(65536);
  float* uB1    = alloc(65536);
  float* h1     = alloc(65536);
  float* h1s    = alloc(65536);
  float* drive2 = alloc(131072);
  float* uA2    = alloc(131072);
  float* uB2    = alloc(131072);
  float* bars   = alloc(1024);       // 2 barrier states (288 ints each, padded)
  float* p0     = alloc(32768);
  float* b0     = alloc(32768);
  float* c1     = alloc(65536);
  float* p1     = alloc(16384);
  float* bb1    = alloc(16384);
  float* c2     = alloc(32768);
  float* p2     = alloc(8192);
  float* bb2    = alloc(8192);
  float* c3     = alloc(16384);
  float* p3     = alloc(4096);
  float* bb3    = alloc(4096);
  float* f1     = alloc(2048);
  int* bar1 = (int*)bars;
  int* bar2 = (int*)bars + 512;

  // ---- setup
  standardize_kernel<<<4, 256, 0, stream>>>(x, xs, 3 * 32 * 32);
  { int tot = 16 * 16 * 108;
    gram_kernel<<<(tot + 255) / 256, 256, 0, stream>>>(w_lca1, Gp1, 16, 3); }
  { int tot = 32 * 32 * 108;
    gram_kernel<<<(tot + 255) / 256, 256, 0, stream>>>(w_lca2, Gp2, 32, 16); }
  conv5x5_kernel<<<(65536 + 255) / 256, 256, 0, stream>>>(
      xs, w_lca1, nullptr, drive1, 4, 3, 16, 32, 32, 0);
  zero_kernel<<<(65536 + 255) / 256, 256, 0, stream>>>(uA1, 65536);
  zero_kernel<<<4, 256, 0, stream>>>(bars, 1024);

  // ---- LCA1: one persistent kernel, 500 iterations, 256 blocks (1/CU)
  lca_persistent_kernel<16><<<2 * 32 * 4, 128, 0, stream>>>(
      drive1, uA1, uB1, Gp1, bar1, 500);
  // final u in uA1 (500 even); a1 = relu(u-l) folded into BN1's transform
  bn_kernel<true><<<16, 256, 0, stream>>>(uA1, h1, bn1_g, bn1_b, 16, 1024, 4);

  // ---- LCA2 setup
  standardize_kernel<<<4, 256, 0, stream>>>(h1, h1s, 16 * 32 * 32);
  conv5x5_kernel<<<(131072 + 255) / 256, 256, 0, stream>>>(
      h1s, w_lca2, nullptr, drive2, 4, 16, 32, 32, 32, 0);
  zero_kernel<<<(131072 + 255) / 256, 256, 0, stream>>>(uA2, 131072);

  // ---- LCA2: persistent, 512 blocks (2/CU, all SIMDs covered)
  lca_persistent_kernel<32><<<4 * 32 * 4, 128, 0, stream>>>(
      drive2, uA2, uB2, Gp2, bar2, 500);
  // a2 = relu(u-l) folded into pool transform
  maxpool_kernel<true><<<(32768 + 255) / 256, 256, 0, stream>>>(uA2, p0, 4, 32, 16, 16);
  bn_kernel<false><<<32, 256, 0, stream>>>(p0, b0, bn2_g, bn2_b, 32, 256, 4);

  // ---- conv tail
  conv5x5_kernel<<<(65536 + 255) / 256, 256, 0, stream>>>(
      b0, w_conv1, b_conv1, c1, 4, 32, 64, 16, 16, 1);
  maxpool_kernel<false><<<(16384 + 255) / 256, 256, 0, stream>>>(c1, p1, 4, 64, 8, 8);
  bn_kernel<false><<<64, 256, 0, stream>>>(p1, bb1, bn3_g, bn3_b, 64, 64, 4);

  conv5x5_kernel<<<(32768 + 255) / 256, 256, 0, stream>>>(
      bb1, w_conv2, b_conv2, c2, 4, 64, 128, 8, 8, 1);
  maxpool_kernel<false><<<(8192 + 255) / 256, 256, 0, stream>>>(c2, p2, 4, 128, 4, 4);
  bn_kernel<false><<<128, 256, 0, stream>>>(p2, bb2, bn4_g, bn4_b, 128, 16, 4);

  conv5x5_kernel<<<(16384 + 255) / 256, 256, 0, stream>>>(
      bb2, w_conv3, b_conv3, c3, 4, 128, 256, 4, 4, 1);
  maxpool_kernel<false><<<(4096 + 255) / 256, 256, 0, stream>>>(c3, p3, 4, 256, 2, 2);
  bn_kernel<false><<<256, 256, 0, stream>>>(p3, bb3, bn5_g, bn5_b, 256, 4, 4);

  // ---- FC head
  fc_kernel<true><<<dim3(512, 4), 64, 0, stream>>>(bb3, w_fc1, b_fc1, f1, 1024);
  fc_kernel<false><<<dim3(10, 4), 64, 0, stream>>>(f1, w_fc2, b_fc2, outp, 512);

  (void)in_sizes; (void)n_in; (void)out_size; (void)ws_size;
}

// Round 3
// 20739.488 us; speedup vs baseline: 3.8289x; 3.8289x over previous
//
#include <hip/hip_runtime.h>
#include <cstddef>

static constexpr float LCA_LAMBDA = 0.5f;
static constexpr float LCA_ETA    = 1.0f / 1000.0f;

// ---------------------------------------------------------------- utilities

__global__ void zero_kernel(float* __restrict__ p, int n) {
  int i = blockIdx.x * blockDim.x + threadIdx.x;
  if (i < n) p[i] = 0.f;
}

// per-sample standardize over C*H*W (population std, eps 1e-8 on std)
__global__ __launch_bounds__(256) void standardize_kernel(
    const float* __restrict__ in, float* __restrict__ out, int CHW) {
  int n = blockIdx.x;
  const float* src = in + (size_t)n * CHW;
  float* dst = out + (size_t)n * CHW;
  int t = threadIdx.x;
  float s = 0.f, ss = 0.f;
  for (int i = t; i < CHW; i += 256) { float v = src[i]; s += v; ss += v * v; }
  __shared__ float red0[256], red1[256];
  red0[t] = s; red1[t] = ss;
  __syncthreads();
  for (int off = 128; off > 0; off >>= 1) {
    if (t < off) { red0[t] += red0[t + off]; red1[t] += red1[t + off]; }
    __syncthreads();
  }
  float m = red0[0] / (float)CHW;
  float var = red1[0] / (float)CHW - m * m;
  var = fmaxf(var, 0.f);
  float inv = 1.0f / (sqrtf(var) + 1e-8f);
  for (int i = t; i < CHW; i += 256) dst[i] = (src[i] - m) * inv;
}

// BatchNorm2d training-mode math over (N,H,W) per channel; optional input
// transform a=relu(u-lambda) (used to read LCA's final u directly).
template <bool TRANSFORM>
__global__ __launch_bounds__(256) void bn_kernel(
    const float* __restrict__ in, float* __restrict__ out,
    const float* __restrict__ gamma, const float* __restrict__ beta,
    int C, int HW, int N) {
  int c = blockIdx.x;
  int t = threadIdx.x;
  float s = 0.f, ss = 0.f;
  for (int n = 0; n < N; ++n) {
    const float* src = in + ((size_t)n * C + c) * HW;
    for (int i = t; i < HW; i += 256) {
      float v = src[i];
      if (TRANSFORM) v = fmaxf(v - LCA_LAMBDA, 0.f);
      s += v; ss += v * v;
    }
  }
  __shared__ float red0[256], red1[256];
  red0[t] = s; red1[t] = ss;
  __syncthreads();
  for (int off = 128; off > 0; off >>= 1) {
    if (t < off) { red0[t] += red0[t + off]; red1[t] += red1[t + off]; }
    __syncthreads();
  }
  float cnt = (float)(N * HW);
  float m = red0[0] / cnt;
  float var = red1[0] / cnt - m * m;
  var = fmaxf(var, 0.f);
  float scale = gamma[c] * rsqrtf(var + 1e-5f);
  float shift = beta[c] - m * scale;
  for (int n = 0; n < N; ++n) {
    const float* src = in + ((size_t)n * C + c) * HW;
    float* dst = out + ((size_t)n * C + c) * HW;
    for (int i = t; i < HW; i += 256) {
      float v = src[i];
      if (TRANSFORM) v = fmaxf(v - LCA_LAMBDA, 0.f);
      dst[i] = v * scale + shift;
    }
  }
}

// Feature Gram kernel G[i][j][p][q] = sum_{c,ky,kx} w[i,c,p+ky-4,q+kx-4]*w[j,c,ky,kx]
// stored padded: Gp[i][j][p][12] (q 0..8 valid, 9..11 zero) for float4 loads.
__global__ void gram_kernel(const float* __restrict__ w, float* __restrict__ Gp,
                            int F, int Cin) {
  int idx = blockIdx.x * blockDim.x + threadIdx.x;
  int tot = F * F * 9 * 12;
  if (idx >= tot) return;
  int q = idx % 12;
  int p = (idx / 12) % 9;
  int j = (idx / 108) % F;
  int i = idx / (108 * F);
  float acc = 0.f;
  if (q < 9) {
    int ky0 = max(0, 4 - p), ky1 = min(4, 8 - p);
    int kx0 = max(0, 4 - q), kx1 = min(4, 8 - q);
    for (int c = 0; c < Cin; ++c) {
      const float* wi = w + ((size_t)i * Cin + c) * 25;
      const float* wj = w + ((size_t)j * Cin + c) * 25;
      for (int ky = ky0; ky <= ky1; ++ky)
        for (int kx = kx0; kx <= kx1; ++kx)
          acc += wi[(p + ky - 4) * 5 + (q + kx - 4)] * wj[ky * 5 + kx];
    }
  }
  Gp[idx] = acc;
}

// generic 5x5 pad-2 cross-correlation (NCHW / OIHW), optional bias+relu
__global__ void conv5x5_kernel(const float* __restrict__ in,
                               const float* __restrict__ w,
                               const float* __restrict__ bias,
                               float* __restrict__ out,
                               int N, int Ci, int Co, int H, int W, int do_relu) {
  int idx = blockIdx.x * blockDim.x + threadIdx.x;
  int tot = N * Co * H * W;
  if (idx >= tot) return;
  int x = idx % W;
  int y = (idx / W) % H;
  int co = (idx / (W * H)) % Co;
  int n = idx / (W * H * Co);
  float acc = bias ? bias[co] : 0.f;
  for (int c = 0; c < Ci; ++c) {
    const float* ip = in + ((size_t)n * Ci + c) * H * W;
    const float* wp = w + ((size_t)co * Ci + c) * 25;
#pragma unroll
    for (int ky = 0; ky < 5; ++ky) {
      int yy = y + ky - 2;
      if (yy < 0 || yy >= H) continue;
#pragma unroll
      for (int kx = 0; kx < 5; ++kx) {
        int xx = x + kx - 2;
        if (xx < 0 || xx >= W) continue;
        acc = fmaf(ip[yy * W + xx], wp[ky * 5 + kx], acc);
      }
    }
  }
  if (do_relu) acc = fmaxf(acc, 0.f);
  out[idx] = acc;
}

template <bool TRANSFORM>
__global__ void maxpool_kernel(const float* __restrict__ in, float* __restrict__ out,
                               int N, int C, int Ho, int Wo) {
  int idx = blockIdx.x * blockDim.x + threadIdx.x;
  int tot = N * C * Ho * Wo;
  if (idx >= tot) return;
  int x = idx % Wo;
  int y = (idx / Wo) % Ho;
  int c = (idx / (Wo * Ho)) % C;
  int n = idx / (Wo * Ho * C);
  int H = Ho * 2, W = Wo * 2;
  const float* ip = in + (((size_t)n * C + c) * H + 2 * y) * W + 2 * x;
  float v0 = ip[0], v1 = ip[1], v2 = ip[W], v3 = ip[W + 1];
  if (TRANSFORM) {
    v0 = fmaxf(v0 - LCA_LAMBDA, 0.f);
    v1 = fmaxf(v1 - LCA_LAMBDA, 0.f);
    v2 = fmaxf(v2 - LCA_LAMBDA, 0.f);
    v3 = fmaxf(v3 - LCA_LAMBDA, 0.f);
  }
  out[idx] = fmaxf(fmaxf(v0, v1), fmaxf(v2, v3));
}

template <bool RELU>
__global__ __launch_bounds__(64) void fc_kernel(
    const float* __restrict__ in, const float* __restrict__ w,
    const float* __restrict__ bias, float* __restrict__ out, int K) {
  int o = blockIdx.x;   // output feature
  int n = blockIdx.y;   // sample
  int Osz = gridDim.x;
  const float* ip = in + (size_t)n * K;
  const float* wp = w + (size_t)o * K;
  float s = 0.f;
  for (int k = threadIdx.x; k < K; k += 64) s = fmaf(ip[k], wp[k], s);
  for (int off = 32; off > 0; off >>= 1) s += __shfl_down(s, off, 64);
  if (threadIdx.x == 0) {
    s += bias[o];
    if (RELU) s = fmaxf(s, 0.f);
    out[(size_t)n * Osz + o] = s;
  }
}

// ------------------------------------------------- agent-coherent u access
// Relaxed AGENT-scope atomics compile to sc0|sc1 load/store: they read/write
// the coherence point (LLC) directly, bypassing the non-coherent per-XCD L2.
// No buffer_wbl2 / buffer_inv is ever emitted -> G and drive stay L2-warm.
__device__ __forceinline__ float load_agent(const float* p) {
  return __hip_atomic_load((const float*)p, __ATOMIC_RELAXED,
                           __HIP_MEMORY_SCOPE_AGENT);
}
__device__ __forceinline__ void store_agent(float* p, float v) {
  __hip_atomic_store(p, v, __ATOMIC_RELAXED, __HIP_MEMORY_SCOPE_AGENT);
}

// ----------------------------------------------------------- grid barrier
// Pure-relaxed two-level generation barrier: no fences, no cache ops.
// Ordering argument (hardware, in-order issue per wave):
//  - __syncthreads() drains vmcnt -> this block's agent stores are at LLC
//    before the arrival add issues.
//  - empty-asm use of g forces the gen-read's s_waitcnt before the add.
//  - s_waitcnt(0) after each reset store orders it before the next-level add.
// bar layout (ints): leaf[l] at l*64 (l<16), root at 1024, gen at 1088.
__device__ __forceinline__ void grid_barrier(int* bar, int bid, int per_leaf) {
  __syncthreads();
  if (threadIdx.x == 0) {
    int* leaf = bar + ((bid & 15) << 6);
    int* root = bar + 1024;
    int* gen  = bar + 1088;
    int g = __hip_atomic_load(gen, __ATOMIC_RELAXED, __HIP_MEMORY_SCOPE_AGENT);
    asm volatile("" : "+v"(g));  // complete gen read before arrival add
    if (__hip_atomic_fetch_add(leaf, 1, __ATOMIC_RELAXED,
                               __HIP_MEMORY_SCOPE_AGENT) == per_leaf - 1) {
      __hip_atomic_store(leaf, 0, __ATOMIC_RELAXED, __HIP_MEMORY_SCOPE_AGENT);
      __builtin_amdgcn_s_waitcnt(0);  // leaf reset at LLC before root add
      if (__hip_atomic_fetch_add(root, 1, __ATOMIC_RELAXED,
                                 __HIP_MEMORY_SCOPE_AGENT) == 15) {
        __hip_atomic_store(root, 0, __ATOMIC_RELAXED, __HIP_MEMORY_SCOPE_AGENT);
        __builtin_amdgcn_s_waitcnt(0);  // root reset at LLC before gen bump
        __hip_atomic_fetch_add(gen, 1, __ATOMIC_RELAXED,
                               __HIP_MEMORY_SCOPE_AGENT);
      }
    }
    while (__hip_atomic_load(gen, __ATOMIC_RELAXED, __HIP_MEMORY_SCOPE_AGENT) == g)
      __builtin_amdgcn_s_sleep(2);
  }
  __syncthreads();
}

// ------------------------------------------------------ persistent LCA solve
// Block covers (n, y0..y0+ROWS-1, 8-feature group); waves = ROWS x GSPLIT
// (wave w: row r=w%ROWS, g-part gpart=w/ROWS). Lane: 8 x-groups (4 consecutive
// x) x 8 features. Slab = a=relu(u-lambda) for rows y0-4..y0+ROWS+3, all C g,
// x padded to 40 -> ds_read_b128 windows, addresses uniform in (g,p) across
// the 8 f-lanes (broadcast, conflict-free). u ping-pongs via LLC (agent
// atomics); G/drive via normal cached loads (L2-resident all 500 iters).
// Grid: FG * (32/ROWS) * 4 = 256 blocks for both phases.
template <int C, int FG, int ROWS, int GSPLIT>
__global__ __launch_bounds__(ROWS * GSPLIT * 64) void lca_persistent_kernel(
    const float* __restrict__ drive, float* __restrict__ uA,
    float* __restrict__ uB, const float* __restrict__ Gp,
    int* __restrict__ bar, int iters) {
  constexpr int THREADS = ROWS * GSPLIT * 64;
  constexpr int SR = 8 + ROWS;          // slab rows
  constexpr int GPW = C / GSPLIT;       // g per wave
  constexpr int YB = 32 / ROWS;         // y-blocks
  constexpr int TOT = SR * C * 40;
  __shared__ float slab[TOT];           // [p][g][40]
  __shared__ float4 partial[(GSPLIT - 1) * ROWS * 64];

  const int tid = threadIdx.x;
  const int bid = blockIdx.x;
  const int fg = bid % FG;
  const int yb = (bid / FG) % YB;
  const int n  = bid / (FG * YB);
  const int y0 = yb * ROWS;

  const int w     = tid >> 6;
  const int lane  = tid & 63;
  const int r     = w % ROWS;
  const int gpart = w / ROWS;
  const int xg = lane & 7, x0 = xg * 4;
  const int f  = fg * 8 + (lane >> 3);
  const int y  = y0 + r;

  const size_t o = (((size_t)n * C + f) * 32 + y) * 32 + x0;
  const int per_leaf = (FG * YB * 4) >> 4;

  for (int it = 0; it < iters; ++it) {
    const float* u_in = (it & 1) ? uB : uA;
    float* u_out      = (it & 1) ? uA : uB;
    const float* ub = u_in + (size_t)n * C * 1024;

    // stage a-slab from LLC
    for (int idx = tid; idx < TOT; idx += THREADS) {
      int xs_ = idx % 40;
      int rest = idx / 40;
      int g = rest % C;
      int p = rest / C;
      int yy = y0 + p - 4;
      int xx = xs_ - 4;
      float v = 0.f;
      if (yy >= 0 && yy < 32 && xx >= 0 && xx < 32)
        v = fmaxf(load_agent(&ub[(g * 32 + yy) * 32 + xx]) - LCA_LAMBDA, 0.f);
      slab[idx] = v;
    }
    __syncthreads();

    float acc0 = 0.f, acc1 = 0.f, acc2 = 0.f, acc3 = 0.f;
    const float4* gbase = (const float4*)Gp + (size_t)f * C * 27;
    for (int gi = 0; gi < GPW; ++gi) {
      int g = gpart * GPW + gi;
      const float* srow = &slab[(r * C + g) * 40 + x0];
      const float4* grow = gbase + g * 27;
#pragma unroll
      for (int p = 0; p < 9; ++p) {
        const float* s = srow + (size_t)p * (C * 40);
        float4 a0 = *(const float4*)(s);
        float4 a1 = *(const float4*)(s + 4);
        float4 a2 = *(const float4*)(s + 8);
        float4 g0 = grow[p * 3], g1 = grow[p * 3 + 1], g2 = grow[p * 3 + 2];
        float wv[12] = {a0.x, a0.y, a0.z, a0.w, a1.x, a1.y,
                        a1.z, a1.w, a2.x, a2.y, a2.z, a2.w};
        float gv[9] = {g0.x, g0.y, g0.z, g0.w, g1.x, g1.y, g1.z, g1.w, g2.x};
#pragma unroll
        for (int q = 0; q < 9; ++q) {
          acc0 = fmaf(wv[q + 0], gv[q], acc0);
          acc1 = fmaf(wv[q + 1], gv[q], acc1);
          acc2 = fmaf(wv[q + 2], gv[q], acc2);
          acc3 = fmaf(wv[q + 3], gv[q], acc3);
        }
      }
    }

    if (gpart > 0) {
      partial[((gpart - 1) * ROWS + r) * 64 + lane] =
          make_float4(acc0, acc1, acc2, acc3);
    }
    __syncthreads();
    if (gpart == 0) {
#pragma unroll
      for (int k = 0; k < GSPLIT - 1; ++k) {
        float4 p4 = partial[(k * ROWS + r) * 64 + lane];
        acc0 += p4.x; acc1 += p4.y; acc2 += p4.z; acc3 += p4.w;
      }
      float4 dv = *(const float4*)(drive + o);
      float u0 = load_agent(u_in + o + 0);
      float u1 = load_agent(u_in + o + 1);
      float u2 = load_agent(u_in + o + 2);
      float u3 = load_agent(u_in + o + 3);
      float a;
      a = fmaxf(u0 - LCA_LAMBDA, 0.f);
      store_agent(u_out + o + 0, u0 + LCA_ETA * (dv.x - u0 - acc0 + a));
      a = fmaxf(u1 - LCA_LAMBDA, 0.f);
      store_agent(u_out + o + 1, u1 + LCA_ETA * (dv.y - u1 - acc1 + a));
      a = fmaxf(u2 - LCA_LAMBDA, 0.f);
      store_agent(u_out + o + 2, u2 + LCA_ETA * (dv.z - u2 - acc2 + a));
      a = fmaxf(u3 - LCA_LAMBDA, 0.f);
      store_agent(u_out + o + 3, u3 + LCA_ETA * (dv.w - u3 - acc3 + a));
    }

    grid_barrier(bar, bid, per_leaf);
  }
}

// ------------------------------------------------------------------ launcher

extern "C" void kernel_launch(void* const* d_in, const int* in_sizes, int n_in,
                              void* d_out, int out_size, void* d_ws, size_t ws_size,
                              hipStream_t stream) {
  const float* x       = (const float*)d_in[0];
  const float* w_lca1  = (const float*)d_in[1];
  const float* w_lca2  = (const float*)d_in[2];
  const float* bn1_g   = (const float*)d_in[3];
  const float* bn1_b   = (const float*)d_in[4];
  const float* bn2_g   = (const float*)d_in[5];
  const float* bn2_b   = (const float*)d_in[6];
  const float* w_conv1 = (const float*)d_in[7];
  const float* b_conv1 = (const float*)d_in[8];
  const float* bn3_g   = (const float*)d_in[9];
  const float* bn3_b   = (const float*)d_in[10];
  const float* w_conv2 = (const float*)d_in[11];
  const float* b_conv2 = (const float*)d_in[12];
  const float* bn4_g   = (const float*)d_in[13];
  const float* bn4_b   = (const float*)d_in[14];
  const float* w_conv3 = (const float*)d_in[15];
  const float* b_conv3 = (const float*)d_in[16];
  const float* bn5_g   = (const float*)d_in[17];
  const float* bn5_b   = (const float*)d_in[18];
  const float* w_fc1   = (const float*)d_in[19];
  const float* b_fc1   = (const float*)d_in[20];
  const float* w_fc2   = (const float*)d_in[21];
  const float* b_fc2   = (const float*)d_in[22];
  float* outp = (float*)d_out;

  float* ws = (float*)d_ws;
  size_t off = 0;
  auto alloc = [&](size_t nelem) {
    float* p = ws + off;
    off += (nelem + 63) & ~(size_t)63;
    return p;
  };
  float* xs     = alloc(4 * 3 * 32 * 32);
  float* Gp1    = alloc(16 * 16 * 9 * 12);
  float* Gp2    = alloc(32 * 32 * 9 * 12);
  float* drive1 = alloc(65536);
  float* uA1    = alloc(65536);
  float* uB1    = alloc(65536);
  float* h1     = alloc(65536);
  float* h1s    = alloc(65536);
  float* drive2 = alloc(131072);
  float* uA2    = alloc(131072);
  float* uB2    = alloc(131072);
  float* bars   = alloc(2560);       // 2 barrier states (1152 ints each, padded)
  float* p0     = alloc(32768);
  float* b0     = alloc(32768);
  float* c1     = alloc(65536);
  float* p1     = alloc(16384);
  float* bb1    = alloc(16384);
  float* c2     = alloc(32768);
  float* p2     = alloc(8192);
  float* bb2    = alloc(8192);
  float* c3     = alloc(16384);
  float* p3     = alloc(4096);
  float* bb3    = alloc(4096);
  float* f1     = alloc(2048);
  int* bar1 = (int*)bars;
  int* bar2 = (int*)bars + 1280;

  // ---- setup
  standardize_kernel<<<4, 256, 0, stream>>>(x, xs, 3 * 32 * 32);
  { int tot = 16 * 16 * 108;
    gram_kernel<<<(tot + 255) / 256, 256, 0, stream>>>(w_lca1, Gp1, 16, 3); }
  { int tot = 32 * 32 * 108;
    gram_kernel<<<(tot + 255) / 256, 256, 0, stream>>>(w_lca2, Gp2, 32, 16); }
  conv5x5_kernel<<<(65536 + 255) / 256, 256, 0, stream>>>(
      xs, w_lca1, nullptr, drive1, 4, 3, 16, 32, 32, 0);
  zero_kernel<<<(65536 + 255) / 256, 256, 0, stream>>>(uA1, 65536);
  zero_kernel<<<10, 256, 0, stream>>>(bars, 2560);

  // ---- LCA1: persistent, 256 blocks x 256 thr (1 row, 4-way g-split)
  lca_persistent_kernel<16, 2, 1, 4><<<256, 256, 0, stream>>>(
      drive1, uA1, uB1, Gp1, bar1, 500);
  // final u in uA1 (500 even); a1 = relu(u-l) folded into BN1's transform
  bn_kernel<true><<<16, 256, 0, stream>>>(uA1, h1, bn1_g, bn1_b, 16, 1024, 4);

  // ---- LCA2 setup
  standardize_kernel<<<4, 256, 0, stream>>>(h1, h1s, 16 * 32 * 32);
  conv5x5_kernel<<<(131072 + 255) / 256, 256, 0, stream>>>(
      h1s, w_lca2, nullptr, drive2, 4, 16, 32, 32, 32, 0);
  zero_kernel<<<(131072 + 255) / 256, 256, 0, stream>>>(uA2, 131072);

  // ---- LCA2: persistent, 256 blocks x 512 thr (2 rows, 4-way g-split)
  lca_persistent_kernel<32, 4, 2, 4><<<256, 512, 0, stream>>>(
      drive2, uA2, uB2, Gp2, bar2, 500);
  // a2 = relu(u-l) folded into pool transform
  maxpool_kernel<true><<<(32768 + 255) / 256, 256, 0, stream>>>(uA2, p0, 4, 32, 16, 16);
  bn_kernel<false><<<32, 256, 0, stream>>>(p0, b0, bn2_g, bn2_b, 32, 256, 4);

  // ---- conv tail
  conv5x5_kernel<<<(65536 + 255) / 256, 256, 0, stream>>>(
      b0, w_conv1, b_conv1, c1, 4, 32, 64, 16, 16, 1);
  maxpool_kernel<false><<<(16384 + 255) / 256, 256, 0, stream>>>(c1, p1, 4, 64, 8, 8);
  bn_kernel<false><<<64, 256, 0, stream>>>(p1, bb1, bn3_g, bn3_b, 64, 64, 4);

  conv5x5_kernel<<<(32768 + 255) / 256, 256, 0, stream>>>(
      bb1, w_conv2, b_conv2, c2, 4, 64, 128, 8, 8, 1);
  maxpool_kernel<false><<<(8192 + 255) / 256, 256, 0, stream>>>(c2, p2, 4, 128, 4, 4);
  bn_kernel<false><<<128, 256, 0, stream>>>(p2, bb2, bn4_g, bn4_b, 128, 16, 4);

  conv5x5_kernel<<<(16384 + 255) / 256, 256, 0, stream>>>(
      bb2, w_conv3, b_conv3, c3, 4, 128, 256, 4, 4, 1);
  maxpool_kernel<false><<<(4096 + 255) / 256, 256, 0, stream>>>(c3, p3, 4, 256, 2, 2);
  bn_kernel<false><<<256, 256, 0, stream>>>(p3, bb3, bn5_g, bn5_b, 256, 4, 4);

  // ---- FC head
  fc_kernel<true><<<dim3(512, 4), 64, 0, stream>>>(bb3, w_fc1, b_fc1, f1, 1024);
  fc_kernel<false><<<dim3(10, 4), 64, 0, stream>>>(f1, w_fc2, b_fc2, outp, 512);

  (void)in_sizes; (void)n_in; (void)out_size; (void)ws_size;
}

// Round 4
// 10537.225 us; speedup vs baseline: 7.5361x; 1.9682x over previous
//
#include <hip/hip_runtime.h>
#include <cstddef>

static constexpr float LCA_LAMBDA = 0.5f;
static constexpr float LCA_ETA    = 1.0f / 1000.0f;

typedef float f32x4 __attribute__((ext_vector_type(4)));

// 16B load/store straight to/from the coherence point (LLC): sc0 sc1 bypass
// L1/L2 so cross-XCD ping-pong data is always fresh and never pollutes L2
// (G and drive stay L2-warm). vmcnt is drained manually (wait_vm0 + reg tie).
__device__ __forceinline__ f32x4 llc_load4(const float* p) {
  f32x4 r;
  asm volatile("global_load_dwordx4 %0, %1, off sc0 sc1" : "=v"(r) : "v"(p));
  return r;
}
__device__ __forceinline__ void llc_store4(float* p, f32x4 v) {
  asm volatile("global_store_dwordx4 %0, %1, off sc0 sc1" :: "v"(p), "v"(v)
               : "memory");
}
__device__ __forceinline__ void wait_vm0() {
  asm volatile("s_waitcnt vmcnt(0)" ::: "memory");
}

// ---------------------------------------------------------------- utilities

__global__ void zero_kernel(float* __restrict__ p, int n) {
  int i = blockIdx.x * blockDim.x + threadIdx.x;
  if (i < n) p[i] = 0.f;
}

__global__ __launch_bounds__(256) void standardize_kernel(
    const float* __restrict__ in, float* __restrict__ out, int CHW) {
  int n = blockIdx.x;
  const float* src = in + (size_t)n * CHW;
  float* dst = out + (size_t)n * CHW;
  int t = threadIdx.x;
  float s = 0.f, ss = 0.f;
  for (int i = t; i < CHW; i += 256) { float v = src[i]; s += v; ss += v * v; }
  __shared__ float red0[256], red1[256];
  red0[t] = s; red1[t] = ss;
  __syncthreads();
  for (int off = 128; off > 0; off >>= 1) {
    if (t < off) { red0[t] += red0[t + off]; red1[t] += red1[t + off]; }
    __syncthreads();
  }
  float m = red0[0] / (float)CHW;
  float var = red1[0] / (float)CHW - m * m;
  var = fmaxf(var, 0.f);
  float inv = 1.0f / (sqrtf(var) + 1e-8f);
  for (int i = t; i < CHW; i += 256) dst[i] = (src[i] - m) * inv;
}

template <bool TRANSFORM>
__global__ __launch_bounds__(256) void bn_kernel(
    const float* __restrict__ in, float* __restrict__ out,
    const float* __restrict__ gamma, const float* __restrict__ beta,
    int C, int HW, int N) {
  int c = blockIdx.x;
  int t = threadIdx.x;
  float s = 0.f, ss = 0.f;
  for (int n = 0; n < N; ++n) {
    const float* src = in + ((size_t)n * C + c) * HW;
    for (int i = t; i < HW; i += 256) {
      float v = src[i];
      if (TRANSFORM) v = fmaxf(v - LCA_LAMBDA, 0.f);
      s += v; ss += v * v;
    }
  }
  __shared__ float red0[256], red1[256];
  red0[t] = s; red1[t] = ss;
  __syncthreads();
  for (int off = 128; off > 0; off >>= 1) {
    if (t < off) { red0[t] += red0[t + off]; red1[t] += red1[t + off]; }
    __syncthreads();
  }
  float cnt = (float)(N * HW);
  float m = red0[0] / cnt;
  float var = red1[0] / cnt - m * m;
  var = fmaxf(var, 0.f);
  float scale = gamma[c] * rsqrtf(var + 1e-5f);
  float shift = beta[c] - m * scale;
  for (int n = 0; n < N; ++n) {
    const float* src = in + ((size_t)n * C + c) * HW;
    float* dst = out + ((size_t)n * C + c) * HW;
    for (int i = t; i < HW; i += 256) {
      float v = src[i];
      if (TRANSFORM) v = fmaxf(v - LCA_LAMBDA, 0.f);
      dst[i] = v * scale + shift;
    }
  }
}

// G[i][j][p][q], padded q-stride 12 for aligned float4 loads.
__global__ void gram_kernel(const float* __restrict__ w, float* __restrict__ Gp,
                            int F, int Cin) {
  int idx = blockIdx.x * blockDim.x + threadIdx.x;
  int tot = F * F * 9 * 12;
  if (idx >= tot) return;
  int q = idx % 12;
  int p = (idx / 12) % 9;
  int j = (idx / 108) % F;
  int i = idx / (108 * F);
  float acc = 0.f;
  if (q < 9) {
    int ky0 = max(0, 4 - p), ky1 = min(4, 8 - p);
    int kx0 = max(0, 4 - q), kx1 = min(4, 8 - q);
    for (int c = 0; c < Cin; ++c) {
      const float* wi = w + ((size_t)i * Cin + c) * 25;
      const float* wj = w + ((size_t)j * Cin + c) * 25;
      for (int ky = ky0; ky <= ky1; ++ky)
        for (int kx = kx0; kx <= kx1; ++kx)
          acc += wi[(p + ky - 4) * 5 + (q + kx - 4)] * wj[ky * 5 + kx];
    }
  }
  Gp[idx] = acc;
}

__global__ void conv5x5_kernel(const float* __restrict__ in,
                               const float* __restrict__ w,
                               const float* __restrict__ bias,
                               float* __restrict__ out,
                               int N, int Ci, int Co, int H, int W, int do_relu) {
  int idx = blockIdx.x * blockDim.x + threadIdx.x;
  int tot = N * Co * H * W;
  if (idx >= tot) return;
  int x = idx % W;
  int y = (idx / W) % H;
  int co = (idx / (W * H)) % Co;
  int n = idx / (W * H * Co);
  float acc = bias ? bias[co] : 0.f;
  for (int c = 0; c < Ci; ++c) {
    const float* ip = in + ((size_t)n * Ci + c) * H * W;
    const float* wp = w + ((size_t)co * Ci + c) * 25;
#pragma unroll
    for (int ky = 0; ky < 5; ++ky) {
      int yy = y + ky - 2;
      if (yy < 0 || yy >= H) continue;
#pragma unroll
      for (int kx = 0; kx < 5; ++kx) {
        int xx = x + kx - 2;
        if (xx < 0 || xx >= W) continue;
        acc = fmaf(ip[yy * W + xx], wp[ky * 5 + kx], acc);
      }
    }
  }
  if (do_relu) acc = fmaxf(acc, 0.f);
  out[idx] = acc;
}

template <bool TRANSFORM>
__global__ void maxpool_kernel(const float* __restrict__ in, float* __restrict__ out,
                               int N, int C, int Ho, int Wo) {
  int idx = blockIdx.x * blockDim.x + threadIdx.x;
  int tot = N * C * Ho * Wo;
  if (idx >= tot) return;
  int x = idx % Wo;
  int y = (idx / Wo) % Ho;
  int c = (idx / (Wo * Ho)) % C;
  int n = idx / (Wo * Ho * C);
  int H = Ho * 2, W = Wo * 2;
  const float* ip = in + (((size_t)n * C + c) * H + 2 * y) * W + 2 * x;
  float v0 = ip[0], v1 = ip[1], v2 = ip[W], v3 = ip[W + 1];
  if (TRANSFORM) {
    v0 = fmaxf(v0 - LCA_LAMBDA, 0.f);
    v1 = fmaxf(v1 - LCA_LAMBDA, 0.f);
    v2 = fmaxf(v2 - LCA_LAMBDA, 0.f);
    v3 = fmaxf(v3 - LCA_LAMBDA, 0.f);
  }
  out[idx] = fmaxf(fmaxf(v0, v1), fmaxf(v2, v3));
}

template <bool RELU>
__global__ __launch_bounds__(64) void fc_kernel(
    const float* __restrict__ in, const float* __restrict__ w,
    const float* __restrict__ bias, float* __restrict__ out, int K) {
  int o = blockIdx.x;
  int n = blockIdx.y;
  int Osz = gridDim.x;
  const float* ip = in + (size_t)n * K;
  const float* wp = w + (size_t)o * K;
  float s = 0.f;
  for (int k = threadIdx.x; k < K; k += 64) s = fmaf(ip[k], wp[k], s);
  for (int off = 32; off > 0; off >>= 1) s += __shfl_down(s, off, 64);
  if (threadIdx.x == 0) {
    s += bias[o];
    if (RELU) s = fmaxf(s, 0.f);
    out[(size_t)n * Osz + o] = s;
  }
}

// ----------------------------------------------------------- grid barrier
// Pure-relaxed two-level generation barrier (proven correct in R3): no
// fences, no cache maintenance. thread0 drains its wave's asm vmem stores
// (wait_vm0) before arriving; compiler-emitted vmcnt waits at the two
// __syncthreads cover all other waves' memory ops.
__device__ __forceinline__ void grid_barrier(int* bar, int bid, int per_leaf) {
  __syncthreads();
  if (threadIdx.x == 0) {
    wait_vm0();  // epilogue sc-stores at LLC before arrival
    int* leaf = bar + ((bid & 15) << 6);
    int* root = bar + 1024;
    int* gen  = bar + 1088;
    int g = __hip_atomic_load(gen, __ATOMIC_RELAXED, __HIP_MEMORY_SCOPE_AGENT);
    asm volatile("" : "+v"(g));
    if (__hip_atomic_fetch_add(leaf, 1, __ATOMIC_RELAXED,
                               __HIP_MEMORY_SCOPE_AGENT) == per_leaf - 1) {
      __hip_atomic_store(leaf, 0, __ATOMIC_RELAXED, __HIP_MEMORY_SCOPE_AGENT);
      __builtin_amdgcn_s_waitcnt(0);
      if (__hip_atomic_fetch_add(root, 1, __ATOMIC_RELAXED,
                                 __HIP_MEMORY_SCOPE_AGENT) == 15) {
        __hip_atomic_store(root, 0, __ATOMIC_RELAXED, __HIP_MEMORY_SCOPE_AGENT);
        __builtin_amdgcn_s_waitcnt(0);
        __hip_atomic_fetch_add(gen, 1, __ATOMIC_RELAXED,
                               __HIP_MEMORY_SCOPE_AGENT);
      }
    }
    while (__hip_atomic_load(gen, __ATOMIC_RELAXED, __HIP_MEMORY_SCOPE_AGENT) == g)
      __builtin_amdgcn_s_sleep(1);
  }
  __syncthreads();
}

// ------------------------------------------------------ persistent LCA solve
// 500 iterations in one kernel, u ping-pong via LLC (sc0 sc1 16B asm ops),
// one relaxed grid barrier per iteration. 256 blocks x 512 thr (8 waves =
// 2/SIMD for latency hiding). Wave lane = 4 xg x 16 f; 8 waves split the g
// sum (GSPLIT=8), partials combined in LDS. Slab: a=relu(u-lambda) rows
// y-4..y+4, all C, x padded (+4 both sides) -> aligned ds_read_b128 windows,
// broadcast across the 16 f-lanes (conflict-free). XH=1 (LCA2): lane computes
// 8 consecutive x (72 FMA / 4 b128); XH=2 (LCA1): half-row blocks, 4 x/lane.
template <int C, int FG, int XH>
__global__ __launch_bounds__(512, 2) void lca_persistent_kernel(
    const float* __restrict__ drive, float* __restrict__ uA,
    float* __restrict__ uB, const float* __restrict__ Gp,
    int* __restrict__ bar, int iters) {
  constexpr int GSPLIT  = 8;
  constexpr int THREADS = 512;
  constexpr int GPW    = C / GSPLIT;      // g per wave (4 / 2)
  constexpr int XSPAN  = 32 / XH;         // x extent per block (32 / 16)
  constexpr int XW     = XSPAN / 4;       // outputs per lane (8 / 4)
  constexpr int ROWLEN = XSPAN + 8;       // padded slab row (40 / 24)
  constexpr int SX4    = (XH == 1) ? 8 : 6;  // staged float4 per row
  constexpr int TOT4   = 9 * C * SX4;
  constexpr int ITEMS  = (TOT4 + THREADS - 1) / THREADS;
  constexpr int PP     = XW / 4;          // output float4 per lane (2 / 1)
  constexpr int NW     = XW + 8;          // window floats (16 / 12)

  __shared__ alignas(16) float slab[9 * C * ROWLEN];
  __shared__ alignas(16) f32x4 partial[PP * (GSPLIT - 1) * 64];

  const int tid = threadIdx.x;
  const int bid = blockIdx.x;
  const int fg = bid % FG;
  const int xh = (bid / FG) % XH;
  const int y  = (bid / (FG * XH)) % 32;
  const int n  = bid / (FG * XH * 32);

  const int gpart = tid >> 6;
  const int lane  = tid & 63;
  const int xg = lane & 3;
  const int f  = fg * 16 + (lane >> 2);
  const int x0 = xh * XSPAN + xg * XW;

  // XH==1 layout has fixed zero pads at both row edges: write once.
  if (XH == 1) {
    const f32x4 z = {0.f, 0.f, 0.f, 0.f};
    for (int idx = tid; idx < 9 * C * 2; idx += THREADS) {
      int row = idx >> 1;
      int side = (idx & 1) * (ROWLEN - 4);
      *(f32x4*)&slab[row * ROWLEN + side] = z;
    }
  }

  const size_t o = (((size_t)n * C + f) * 32 + y) * 32 + x0;
  const float* gbase = Gp + (size_t)f * C * 108;

  for (int it = 0; it < iters; ++it) {
    const float* u_in = (it & 1) ? uB : uA;
    float* u_out      = (it & 1) ? uA : uB;
    const float* ub = u_in + (size_t)n * C * 1024;

    // ---- stage slab: batch-issue wide LLC loads, single drain, relu->LDS
    f32x4 sv[ITEMS];
    int  sidx[ITEMS];
    bool sok[ITEMS];
#pragma unroll
    for (int i = 0; i < ITEMS; ++i) {
      int idx = tid + i * THREADS;
      int idc = idx < TOT4 ? idx : 0;
      int x4 = idc % SX4;
      int g  = (idc / SX4) % C;
      int p  = idc / (SX4 * C);
      int yy = y + p - 4;
      int yyc = min(max(yy, 0), 31);
      int xstart = (XH == 1) ? (x4 * 4) : (xh * XSPAN - 4 + x4 * 4);
      int xc = min(max(xstart, 0), 28);
      sv[i] = llc_load4(ub + ((g << 5) + yyc) * 32 + xc);
      sok[i] = (yy >= 0) && (yy < 32) && (xstart >= 0) && (xstart <= 28);
      int slot = (XH == 1) ? (4 + x4 * 4) : (x4 * 4);
      sidx[i] = (p * C + g) * ROWLEN + slot;
    }
    wait_vm0();
#pragma unroll
    for (int i = 0; i < ITEMS; ++i) asm volatile("" : "+v"(sv[i]));
#pragma unroll
    for (int i = 0; i < ITEMS; ++i) {
      int idx = tid + i * THREADS;
      if (idx < TOT4) {
        f32x4 v = sv[i];
        if (!sok[i]) v = f32x4{0.f, 0.f, 0.f, 0.f};
        f32x4 a;
        a.x = fmaxf(v.x - LCA_LAMBDA, 0.f);
        a.y = fmaxf(v.y - LCA_LAMBDA, 0.f);
        a.z = fmaxf(v.z - LCA_LAMBDA, 0.f);
        a.w = fmaxf(v.w - LCA_LAMBDA, 0.f);
        *(f32x4*)&slab[sidx[i]] = a;
      }
    }
    // early epilogue loads: u (LLC) + drive (L2) hidden behind the FMA loop
    f32x4 uv[PP], dvv[PP];
    if (gpart == 0) {
#pragma unroll
      for (int k = 0; k < PP; ++k) {
        uv[k]  = llc_load4(u_in + o + 4 * k);
        dvv[k] = *(const f32x4*)(drive + o + 4 * k);
      }
    }
    __syncthreads();

    // ---- lateral inhibition: this wave's share of the g sum
    float acc[XW];
#pragma unroll
    for (int j = 0; j < XW; ++j) acc[j] = 0.f;
    for (int gi = 0; gi < GPW; ++gi) {
      int g = gpart * GPW + gi;
      const float* srow = &slab[g * ROWLEN + xg * XW];
      const float* grow = gbase + g * 108;
#pragma unroll
      for (int p = 0; p < 9; ++p) {
        const float* s = srow + p * (C * ROWLEN);
        float w[NW];
#pragma unroll
        for (int k = 0; k < NW / 4; ++k)
          *(f32x4*)&w[4 * k] = *(const f32x4*)(s + 4 * k);
        f32x4 g0 = *(const f32x4*)(grow + p * 12);
        f32x4 g1 = *(const f32x4*)(grow + p * 12 + 4);
        f32x4 g2 = *(const f32x4*)(grow + p * 12 + 8);
        float gv[9] = {g0.x, g0.y, g0.z, g0.w, g1.x, g1.y, g1.z, g1.w, g2.x};
#pragma unroll
        for (int q = 0; q < 9; ++q)
#pragma unroll
          for (int j = 0; j < XW; ++j)
            acc[j] = fmaf(w[j + q], gv[q], acc[j]);
      }
    }

    if (gpart > 0) {
#pragma unroll
      for (int k = 0; k < PP; ++k)
        partial[(k * (GSPLIT - 1) + (gpart - 1)) * 64 + lane] =
            f32x4{acc[4 * k], acc[4 * k + 1], acc[4 * k + 2], acc[4 * k + 3]};
    }
    __syncthreads();
    if (gpart == 0) {
      wait_vm0();
#pragma unroll
      for (int k = 0; k < PP; ++k) asm volatile("" : "+v"(uv[k]));
#pragma unroll
      for (int k = 0; k < PP; ++k) {
        float a0 = acc[4 * k], a1 = acc[4 * k + 1];
        float a2 = acc[4 * k + 2], a3 = acc[4 * k + 3];
#pragma unroll
        for (int w2 = 0; w2 < GSPLIT - 1; ++w2) {
          f32x4 pp = partial[(k * (GSPLIT - 1) + w2) * 64 + lane];
          a0 += pp.x; a1 += pp.y; a2 += pp.z; a3 += pp.w;
        }
        f32x4 u4 = uv[k], d4 = dvv[k], r;
        float a;
        a = fmaxf(u4.x - LCA_LAMBDA, 0.f);
        r.x = u4.x + LCA_ETA * (d4.x - u4.x - a0 + a);
        a = fmaxf(u4.y - LCA_LAMBDA, 0.f);
        r.y = u4.y + LCA_ETA * (d4.y - u4.y - a1 + a);
        a = fmaxf(u4.z - LCA_LAMBDA, 0.f);
        r.z = u4.z + LCA_ETA * (d4.z - u4.z - a2 + a);
        a = fmaxf(u4.w - LCA_LAMBDA, 0.f);
        r.w = u4.w + LCA_ETA * (d4.w - u4.w - a3 + a);
        llc_store4(u_out + o + 4 * k, r);
      }
    }
    grid_barrier(bar, bid, 16);
  }
}

// ------------------------------------------------------------------ launcher

extern "C" void kernel_launch(void* const* d_in, const int* in_sizes, int n_in,
                              void* d_out, int out_size, void* d_ws, size_t ws_size,
                              hipStream_t stream) {
  const float* x       = (const float*)d_in[0];
  const float* w_lca1  = (const float*)d_in[1];
  const float* w_lca2  = (const float*)d_in[2];
  const float* bn1_g   = (const float*)d_in[3];
  const float* bn1_b   = (const float*)d_in[4];
  const float* bn2_g   = (const float*)d_in[5];
  const float* bn2_b   = (const float*)d_in[6];
  const float* w_conv1 = (const float*)d_in[7];
  const float* b_conv1 = (const float*)d_in[8];
  const float* bn3_g   = (const float*)d_in[9];
  const float* bn3_b   = (const float*)d_in[10];
  const float* w_conv2 = (const float*)d_in[11];
  const float* b_conv2 = (const float*)d_in[12];
  const float* bn4_g   = (const float*)d_in[13];
  const float* bn4_b   = (const float*)d_in[14];
  const float* w_conv3 = (const float*)d_in[15];
  const float* b_conv3 = (const float*)d_in[16];
  const float* bn5_g   = (const float*)d_in[17];
  const float* bn5_b   = (const float*)d_in[18];
  const float* w_fc1   = (const float*)d_in[19];
  const float* b_fc1   = (const float*)d_in[20];
  const float* w_fc2   = (const float*)d_in[21];
  const float* b_fc2   = (const float*)d_in[22];
  float* outp = (float*)d_out;

  float* ws = (float*)d_ws;
  size_t off = 0;
  auto alloc = [&](size_t nelem) {
    float* p = ws + off;
    off += (nelem + 63) & ~(size_t)63;
    return p;
  };
  float* xs     = alloc(4 * 3 * 32 * 32);
  float* Gp1    = alloc(16 * 16 * 9 * 12);
  float* Gp2    = alloc(32 * 32 * 9 * 12);
  float* drive1 = alloc(65536);
  float* uA1    = alloc(65536);
  float* uB1    = alloc(65536);
  float* h1     = alloc(65536);
  float* h1s    = alloc(65536);
  float* drive2 = alloc(131072);
  float* uA2    = alloc(131072);
  float* uB2    = alloc(131072);
  float* bars   = alloc(2560);
  float* p0     = alloc(32768);
  float* b0     = alloc(32768);
  float* c1     = alloc(65536);
  float* p1     = alloc(16384);
  float* bb1    = alloc(16384);
  float* c2     = alloc(32768);
  float* p2     = alloc(8192);
  float* bb2    = alloc(8192);
  float* c3     = alloc(16384);
  float* p3     = alloc(4096);
  float* bb3    = alloc(4096);
  float* f1     = alloc(2048);
  int* bar1 = (int*)bars;
  int* bar2 = (int*)bars + 1280;

  // ---- setup
  standardize_kernel<<<4, 256, 0, stream>>>(x, xs, 3 * 32 * 32);
  { int tot = 16 * 16 * 108;
    gram_kernel<<<(tot + 255) / 256, 256, 0, stream>>>(w_lca1, Gp1, 16, 3); }
  { int tot = 32 * 32 * 108;
    gram_kernel<<<(tot + 255) / 256, 256, 0, stream>>>(w_lca2, Gp2, 32, 16); }
  conv5x5_kernel<<<(65536 + 255) / 256, 256, 0, stream>>>(
      xs, w_lca1, nullptr, drive1, 4, 3, 16, 32, 32, 0);
  zero_kernel<<<(65536 + 255) / 256, 256, 0, stream>>>(uA1, 65536);
  zero_kernel<<<10, 256, 0, stream>>>(bars, 2560);

  // ---- LCA1: C=16, FG=1, XH=2 (half-row blocks) -> 256 blocks x 512 thr
  lca_persistent_kernel<16, 1, 2><<<256, 512, 0, stream>>>(
      drive1, uA1, uB1, Gp1, bar1, 500);
  bn_kernel<true><<<16, 256, 0, stream>>>(uA1, h1, bn1_g, bn1_b, 16, 1024, 4);

  // ---- LCA2 setup
  standardize_kernel<<<4, 256, 0, stream>>>(h1, h1s, 16 * 32 * 32);
  conv5x5_kernel<<<(131072 + 255) / 256, 256, 0, stream>>>(
      h1s, w_lca2, nullptr, drive2, 4, 16, 32, 32, 32, 0);
  zero_kernel<<<(131072 + 255) / 256, 256, 0, stream>>>(uA2, 131072);

  // ---- LCA2: C=32, FG=2, XH=1 (full-row, 8 x/lane) -> 256 blocks x 512 thr
  lca_persistent_kernel<32, 2, 1><<<256, 512, 0, stream>>>(
      drive2, uA2, uB2, Gp2, bar2, 500);
  maxpool_kernel<true><<<(32768 + 255) / 256, 256, 0, stream>>>(uA2, p0, 4, 32, 16, 16);
  bn_kernel<false><<<32, 256, 0, stream>>>(p0, b0, bn2_g, bn2_b, 32, 256, 4);

  // ---- conv tail
  conv5x5_kernel<<<(65536 + 255) / 256, 256, 0, stream>>>(
      b0, w_conv1, b_conv1, c1, 4, 32, 64, 16, 16, 1);
  maxpool_kernel<false><<<(16384 + 255) / 256, 256, 0, stream>>>(c1, p1, 4, 64, 8, 8);
  bn_kernel<false><<<64, 256, 0, stream>>>(p1, bb1, bn3_g, bn3_b, 64, 64, 4);

  conv5x5_kernel<<<(32768 + 255) / 256, 256, 0, stream>>>(
      bb1, w_conv2, b_conv2, c2, 4, 64, 128, 8, 8, 1);
  maxpool_kernel<false><<<(8192 + 255) / 256, 256, 0, stream>>>(c2, p2, 4, 128, 4, 4);
  bn_kernel<false><<<128, 256, 0, stream>>>(p2, bb2, bn4_g, bn4_b, 128, 16, 4);

  conv5x5_kernel<<<(16384 + 255) / 256, 256, 0, stream>>>(
      bb2, w_conv3, b_conv3, c3, 4, 128, 256, 4, 4, 1);
  maxpool_kernel<false><<<(4096 + 255) / 256, 256, 0, stream>>>(c3, p3, 4, 256, 2, 2);
  bn_kernel<false><<<256, 256, 0, stream>>>(p3, bb3, bn5_g, bn5_b, 256, 4, 4);

  // ---- FC head
  fc_kernel<true><<<dim3(512, 4), 64, 0, stream>>>(bb3, w_fc1, b_fc1, f1, 1024);
  fc_kernel<false><<<dim3(10, 4), 64, 0, stream>>>(f1, w_fc2, b_fc2, outp, 512);

  (void)in_sizes; (void)n_in; (void)out_size; (void)ws_size;
}